// Round 10
// baseline (86.056 us; speedup 1.0000x reference)
//
#include <hip/hip_runtime.h>

#define CLIP 4096
#define H1   2048
#define H2   1024
#define RN   4096
#define H_STEP 2.44140625f   // r_i = H_STEP*(i+1) exactly
#define G1   65536           // Sturm grid points per l

typedef float v2f __attribute__((ext_vector_type(2)));

// ---- monotone float<->uint map for atomic min/max of floats -----------------
__device__ __forceinline__ unsigned fmap(float f) {
    unsigned u = __float_as_uint(f);
    return (u & 0x80000000u) ? ~u : (u | 0x80000000u);
}
__device__ __forceinline__ float funmap(unsigned u) {
    return __uint_as_float((u & 0x80000000u) ? (u & 0x7fffffffu) : ~u);
}
__device__ __forceinline__ void spect_bounds(const unsigned* bu, float& lo, float& cell) {
    float mn = funmap(bu[0]), mx = funmap(bu[1]);
    lo = mn - 1e-3f;                              // Gershgorin: lambda_min >= min ptl
    float hi = mx + 2.33554432f + 1e-3f;          // lambda_max <= max ptl + 2 + 2/r0^2
    cell = (hi - lo) * (1.0f / (float)G1);
}

// ---------------- Layer 1 split-K partials: partA[c][j] ----------------------
__global__ __launch_bounds__(256) void part1(const float* __restrict__ W,
                                             const float* __restrict__ x,
                                             float* __restrict__ partA,
                                             unsigned* __restrict__ bu) {
    if (blockIdx.x == 0 && blockIdx.y == 0 && threadIdx.x == 0) {
        bu[0] = 0xFFFFFFFFu;   // running min (mapped)
        bu[1] = 0u;            // running max (mapped)
    }
    int j = blockIdx.x * 256 + threadIdx.x;       // 8 x-blocks -> j < 2048
    int i0 = blockIdx.y * 64;                     // 64 k-chunks of 64 rows
    const float* Wp = W + (size_t)i0 * H1 + j;
    float acc = 0.f;
#pragma unroll 8
    for (int i = 0; i < 64; ++i)
        acc = fmaf(x[i0 + i], Wp[(size_t)i * H1], acc);   // x uniform -> s_load
    partA[(size_t)blockIdx.y * H1 + j] = acc;
}

// ------- Layer 2, fused: prologue reduces the 16 h1 values this block needs --
__global__ __launch_bounds__(256) void part2f(const float* __restrict__ W,
                                              const float* __restrict__ partA,
                                              const float* __restrict__ b,
                                              float* __restrict__ partB) {
    __shared__ float xs[16];
    int t = threadIdx.x;
    int i_loc = t >> 4, c_loc = t & 15;           // 16 i's x 16 lanes
    int i0 = blockIdx.y * 16;                     // 128 k-chunks of 16 rows
    float s = 0.f;
#pragma unroll
    for (int k = 0; k < 4; ++k)                   // 64 layer-1 partials
        s += partA[(size_t)(c_loc + 16 * k) * H1 + i0 + i_loc];
    s += __shfl_xor(s, 1); s += __shfl_xor(s, 2);
    s += __shfl_xor(s, 4); s += __shfl_xor(s, 8);
    if (c_loc == 0) xs[i_loc] = fmaxf(s + b[i0 + i_loc], 0.f);
    __syncthreads();
    float xv[16];
#pragma unroll
    for (int u = 0; u < 16; ++u) xv[u] = xs[u];
    int j = blockIdx.x * 256 + t;                 // 4 x-blocks -> j < 1024
    const float* Wp = W + (size_t)i0 * H2 + j;
    float acc = 0.f;
#pragma unroll
    for (int i = 0; i < 16; ++i)
        acc = fmaf(xv[i], Wp[(size_t)i * H2], acc);
    partB[(size_t)blockIdx.y * H2 + j] = acc;
}

// ------- Layer 3, fused: prologue reduces the 32 h2 values this block needs --
__global__ __launch_bounds__(256) void part3f(const float* __restrict__ W,
                                              const float* __restrict__ partB,
                                              const float* __restrict__ b,
                                              float* __restrict__ partA) {
    __shared__ float xs[32];
    int t = threadIdx.x;
    int i_loc = t >> 3, c_loc = t & 7;            // 32 i's x 8 lanes
    int i0 = blockIdx.y * 32;                     // 32 k-chunks of 32 rows
    float s = 0.f;
#pragma unroll
    for (int k = 0; k < 16; ++k)                  // 128 layer-2 partials
        s += partB[(size_t)(c_loc + 8 * k) * H2 + i0 + i_loc];
    s += __shfl_xor(s, 1); s += __shfl_xor(s, 2); s += __shfl_xor(s, 4);
    if (c_loc == 0) xs[i_loc] = fmaxf(s + b[i0 + i_loc], 0.f);
    __syncthreads();
    float xv[32];
#pragma unroll
    for (int u = 0; u < 32; ++u) xv[u] = xs[u];
    int j = blockIdx.x * 256 + t;                 // 16 x-blocks -> j < 4096
    const float* Wp = W + (size_t)i0 * RN + j;
    float acc = 0.f;
#pragma unroll
    for (int i = 0; i < 32; ++i)
        acc = fmaf(xv[i], Wp[(size_t)i * RN], acc);
    partA[(size_t)blockIdx.y * RN + j] = acc;
}

// ---- Final fin: ptl -> d_out, interleaved {D0[j],D1[j]} = 2*diag, bounds ----
__global__ __launch_bounds__(256) void fin3(const float* __restrict__ partA,
                                            const float* __restrict__ b,
                                            float* __restrict__ out,
                                            float* __restrict__ Dint,
                                            unsigned* __restrict__ bu) {
    __shared__ float smn[4], smx[4];
    int j = blockIdx.x * 256 + threadIdx.x;
    float s = b[j];
#pragma unroll 8
    for (int c = 0; c < 32; ++c) s += partA[(size_t)c * RN + j];
    out[j] = s;                                   // ptl -> d_out[0:RN]
    float r = H_STEP * (float)(j + 1);
    float base = 2.0f + 2.0f * s;                 // 2*(1 + ptl)
    float2 dpair = make_float2(base, base + 4.0f / (r * r));  // {l=0, l=1}
    reinterpret_cast<float2*>(Dint)[j] = dpair;
    float mn = s, mx = s;
    for (int off = 32; off; off >>= 1) {
        mn = fminf(mn, __shfl_down(mn, off));
        mx = fmaxf(mx, __shfl_down(mx, off));
    }
    int tid = threadIdx.x;
    if ((tid & 63) == 0) { smn[tid >> 6] = mn; smx[tid >> 6] = mx; }
    __syncthreads();
    if (tid == 0) {
        for (int w = 1; w < 4; ++w) { mn = fminf(mn, smn[w]); mx = fmaxf(mx, smx[w]); }
        atomicMin(&bu[0], fmap(mn));
        atomicMax(&bu[1], fmap(mx));
    }
}

// -------- Sturm count: BOTH l=0 and l=1 chains per thread at the same X ------
// q_i = (D_i - X) q_{i-1} - q_{i-2} with D = 2*diag, X = 2*x (no 0.25 coeff).
// LDS holds {D0[i],D1[i]} interleaved, so each float4 load yields two aligned
// v2f operand pairs -> v_pk_add_f32 / v_pk_fma_f32 do 2 chains per instruction.
#define PSTEP(dda, ddb)                                                    \
    {                                                                      \
        v2f dd = {dda, ddb};                                               \
        v2f t = dd - X2;                                                   \
        v2f p = __builtin_elementwise_fma(t, pm1, -pm2);                   \
        rA = __builtin_amdgcn_alignbit(rA, __float_as_uint(p.x), 31);      \
        rB = __builtin_amdgcn_alignbit(rB, __float_as_uint(p.y), 31);      \
        pm2 = pm1; pm1 = p;                                                \
    }

#define CNT16_2                                                            \
    {                                                                      \
        cntA += (unsigned)__builtin_popcount((rA ^ (rA >> 1)) & 0xFFFFu);  \
        cntB += (unsigned)__builtin_popcount((rB ^ (rB >> 1)) & 0xFFFFu);  \
    }

#define RENORM2                                                            \
    {                                                                      \
        unsigned hA = (__float_as_uint(pm1.x) & 0x7fffffffu);              \
        unsigned qA = (__float_as_uint(pm2.x) & 0x7fffffffu);              \
        if (qA > hA) hA = qA;                                              \
        unsigned hB = (__float_as_uint(pm1.y) & 0x7fffffffu);              \
        unsigned qB = (__float_as_uint(pm2.y) & 0x7fffffffu);              \
        if (qB > hB) hB = qB;                                              \
        int eA = 254 - (int)(hA >> 23); eA = eA < 1 ? 1 : eA;              \
        int eB = 254 - (int)(hB >> 23); eB = eB < 1 ? 1 : eB;              \
        v2f sc = {__uint_as_float((unsigned)eA << 23),                     \
                  __uint_as_float((unsigned)eB << 23)};                    \
        pm1 *= sc; pm2 *= sc;                                              \
    }

__global__ __launch_bounds__(256) void stage1(const float* __restrict__ Dint,
                                              const unsigned* __restrict__ bu,
                                              int* __restrict__ counts) {
    __shared__ alignas(16) float ds[2 * RN];      // interleaved {D0,D1}
    for (int i = threadIdx.x; i < 2 * RN / 4; i += 256)
        reinterpret_cast<float4*>(ds)[i] = reinterpret_cast<const float4*>(Dint)[i];
    __syncthreads();

    float lo, cell;
    spect_bounds(bu, lo, cell);
    int j = blockIdx.x * 256 + threadIdx.x;       // 256 blocks -> j < 65536
    float X = 2.0f * (lo + cell * (float)j);
    v2f X2 = {X, X};

    v2f pm1 = {1.f, 1.f}, pm2 = {0.f, 0.f};
    unsigned cntA = 0, cntB = 0, rA = 0, rB = 0;
    const float4* d4 = reinterpret_cast<const float4*>(ds);

    // 32 outer iters x 128 steps (64 float4); inner: 8 groups of 16 steps.
    for (int w = 0; w < 32; ++w) {
        const float4* g = d4 + w * 64;
#pragma unroll
        for (int q = 0; q < 8; ++q) {             // 8 groups x 8 float4 = 64 float4
            float4 v0 = g[q * 8 + 0], v1 = g[q * 8 + 1];
            float4 v2 = g[q * 8 + 2], v3 = g[q * 8 + 3];
            float4 v4 = g[q * 8 + 4], v5 = g[q * 8 + 5];
            float4 v6 = g[q * 8 + 6], v7 = g[q * 8 + 7];
            PSTEP(v0.x, v0.y) PSTEP(v0.z, v0.w)
            PSTEP(v1.x, v1.y) PSTEP(v1.z, v1.w)
            PSTEP(v2.x, v2.y) PSTEP(v2.z, v2.w)
            PSTEP(v3.x, v3.y) PSTEP(v3.z, v3.w)
            PSTEP(v4.x, v4.y) PSTEP(v4.z, v4.w)
            PSTEP(v5.x, v5.y) PSTEP(v5.z, v5.w)
            PSTEP(v6.x, v6.y) PSTEP(v6.z, v6.w)
            PSTEP(v7.x, v7.y) PSTEP(v7.z, v7.w)
            CNT16_2
            RENORM2          // growth <= ~2^96 per 16 steps: safe in f32
        }
    }
    counts[j] = (int)cntA;                        // l = 0
    counts[G1 + j] = (int)cntB;                   // l = 1
}

// ------------- final: bracket search (noise-tolerant) + midpoint -------------
__global__ __launch_bounds__(256) void final_eig(const int* __restrict__ counts,
                                                 const unsigned* __restrict__ bu,
                                                 float* __restrict__ out) {
    int e = blockIdx.x * 256 + threadIdx.x;       // 8192 eigenvalues (l,k)
    int l = e >> 12, k = e & (RN - 1);
    const int* c = counts + (l << 16);
    int lo_i = 0, hi_i = G1 - 1;                  // last j with c[j] <= k
    while (lo_i < hi_i) {
        int mid = (lo_i + hi_i + 1) >> 1;
        if (c[mid] <= k) lo_i = mid; else hi_i = mid - 1;
    }
    while (lo_i > 0 && c[lo_i] > k) --lo_i;       // +-1 noise fixups
    while (lo_i < G1 - 1 && c[lo_i + 1] <= k) ++lo_i;
    float lo, cell;
    spect_bounds(bu, lo, cell);
    out[e] = lo + cell * ((float)lo_i + 0.5f);
}

extern "C" void kernel_launch(void* const* d_in, const int* in_sizes, int n_in,
                              void* d_out, int out_size, void* d_ws, size_t ws_size,
                              hipStream_t stream) {
    const float* energy = (const float*)d_in[0];
    const float* W1 = (const float*)d_in[1];
    const float* b1 = (const float*)d_in[2];
    const float* W2 = (const float*)d_in[3];
    const float* b2 = (const float*)d_in[4];
    const float* W3 = (const float*)d_in[5];
    const float* b3 = (const float*)d_in[6];
    float* out = (float*)d_out;                   // [RN] ptl, then [2*RN] eigenvalues

    float* ws = (float*)d_ws;
    float*    partA  = ws;                        // 131072 f32 (layers 1,3)
    float*    partB  = partA + 131072;            // 131072 f32 (layer 2)
    float*    Dint   = partB + 131072;            // 2*RN f32 interleaved {D0,D1}
    unsigned* bu     = (unsigned*)(Dint + 2 * RN); // 2 u32
    int*      counts = (int*)(bu + 4);            // 2*G1 i32 (512 KB)

    // ---- MLP: 3 GEMVs, fins fused into next layer's prologue ----
    part1 <<<dim3(8, 64),  256, 0, stream>>>(W1, energy, partA, bu);
    part2f<<<dim3(4, 128), 256, 0, stream>>>(W2, partA, b1, partB);
    part3f<<<dim3(16, 32), 256, 0, stream>>>(W3, partB, b2, partA);
    fin3  <<<RN / 256,     256, 0, stream>>>(partA, b3, out, Dint, bu);

    // ---- Eigenvalues: packed-f32 dual-l Sturm multisection ----
    stage1<<<G1 / 256, 256, 0, stream>>>(Dint, bu, counts);
    final_eig<<<2 * RN / 256, 256, 0, stream>>>(counts, bu, out + RN);
}

// Round 11
// 75.908 us; speedup vs baseline: 1.1337x; 1.1337x over previous
//
#include <hip/hip_runtime.h>

#define CLIP 4096
#define H1   2048
#define H2   1024
#define RN   4096
#define H_STEP 2.44140625f   // r_i = H_STEP*(i+1) exactly
#define G1   65536           // Sturm grid points per l (131072 chains = 2 waves/SIMD)

// ---- monotone float<->uint map for atomic min/max of floats -----------------
__device__ __forceinline__ unsigned fmap(float f) {
    unsigned u = __float_as_uint(f);
    return (u & 0x80000000u) ? ~u : (u | 0x80000000u);
}
__device__ __forceinline__ float funmap(unsigned u) {
    return __uint_as_float((u & 0x80000000u) ? (u & 0x7fffffffu) : ~u);
}
__device__ __forceinline__ void spect_bounds(const unsigned* bu, float& lo, float& cell) {
    float mn = funmap(bu[0]), mx = funmap(bu[1]);
    lo = mn - 1e-3f;                              // Gershgorin: lambda_min >= min ptl
    float hi = mx + 2.33554432f + 1e-3f;          // lambda_max <= max ptl + 2 + 2/r0^2
    cell = (hi - lo) * (1.0f / (float)G1);
}

// ---------------- Layer 1 split-K partials: partA[c][j] ----------------------
__global__ __launch_bounds__(256) void part1(const float* __restrict__ W,
                                             const float* __restrict__ x,
                                             float* __restrict__ partA,
                                             unsigned* __restrict__ bu) {
    if (blockIdx.x == 0 && blockIdx.y == 0 && threadIdx.x == 0) {
        bu[0] = 0xFFFFFFFFu;   // running min (mapped)
        bu[1] = 0u;            // running max (mapped)
    }
    int j = blockIdx.x * 256 + threadIdx.x;       // 8 x-blocks -> j < 2048
    int i0 = blockIdx.y * 64;                     // 64 k-chunks of 64 rows
    const float* Wp = W + (size_t)i0 * H1 + j;
    float acc = 0.f;
#pragma unroll 8
    for (int i = 0; i < 64; ++i)
        acc = fmaf(x[i0 + i], Wp[(size_t)i * H1], acc);   // x uniform -> s_load
    partA[(size_t)blockIdx.y * H1 + j] = acc;
}

// ------- Layer 2, fused: prologue reduces the 16 h1 values this block needs --
__global__ __launch_bounds__(256) void part2f(const float* __restrict__ W,
                                              const float* __restrict__ partA,
                                              const float* __restrict__ b,
                                              float* __restrict__ partB) {
    __shared__ float xs[16];
    int t = threadIdx.x;
    int i_loc = t >> 4, c_loc = t & 15;           // 16 i's x 16 lanes
    int i0 = blockIdx.y * 16;                     // 128 k-chunks of 16 rows
    float s = 0.f;
#pragma unroll
    for (int k = 0; k < 4; ++k)                   // 64 layer-1 partials
        s += partA[(size_t)(c_loc + 16 * k) * H1 + i0 + i_loc];
    s += __shfl_xor(s, 1); s += __shfl_xor(s, 2);
    s += __shfl_xor(s, 4); s += __shfl_xor(s, 8);
    if (c_loc == 0) xs[i_loc] = fmaxf(s + b[i0 + i_loc], 0.f);
    __syncthreads();
    float xv[16];
#pragma unroll
    for (int u = 0; u < 16; ++u) xv[u] = xs[u];
    int j = blockIdx.x * 256 + t;                 // 4 x-blocks -> j < 1024
    const float* Wp = W + (size_t)i0 * H2 + j;
    float acc = 0.f;
#pragma unroll
    for (int i = 0; i < 16; ++i)
        acc = fmaf(xv[i], Wp[(size_t)i * H2], acc);
    partB[(size_t)blockIdx.y * H2 + j] = acc;
}

// ------- Layer 3, fused: prologue reduces the 32 h2 values this block needs --
__global__ __launch_bounds__(256) void part3f(const float* __restrict__ W,
                                              const float* __restrict__ partB,
                                              const float* __restrict__ b,
                                              float* __restrict__ partA) {
    __shared__ float xs[32];
    int t = threadIdx.x;
    int i_loc = t >> 3, c_loc = t & 7;            // 32 i's x 8 lanes
    int i0 = blockIdx.y * 32;                     // 32 k-chunks of 32 rows
    float s = 0.f;
#pragma unroll
    for (int k = 0; k < 16; ++k)                  // 128 layer-2 partials
        s += partB[(size_t)(c_loc + 8 * k) * H2 + i0 + i_loc];
    s += __shfl_xor(s, 1); s += __shfl_xor(s, 2); s += __shfl_xor(s, 4);
    if (c_loc == 0) xs[i_loc] = fmaxf(s + b[i0 + i_loc], 0.f);
    __syncthreads();
    float xv[32];
#pragma unroll
    for (int u = 0; u < 32; ++u) xv[u] = xs[u];
    int j = blockIdx.x * 256 + t;                 // 16 x-blocks -> j < 4096
    const float* Wp = W + (size_t)i0 * RN + j;
    float acc = 0.f;
#pragma unroll
    for (int i = 0; i < 32; ++i)
        acc = fmaf(xv[i], Wp[(size_t)i * RN], acc);
    partA[(size_t)blockIdx.y * RN + j] = acc;
}

// ---- Final fin: ptl -> d_out, D0/D1 = 2*diag (contiguous), spectral bounds --
__global__ __launch_bounds__(256) void fin3(const float* __restrict__ partA,
                                            const float* __restrict__ b,
                                            float* __restrict__ out,
                                            float* __restrict__ D,
                                            unsigned* __restrict__ bu) {
    __shared__ float smn[4], smx[4];
    int j = blockIdx.x * 256 + threadIdx.x;
    float s = b[j];
#pragma unroll 8
    for (int c = 0; c < 32; ++c) s += partA[(size_t)c * RN + j];
    out[j] = s;                                   // ptl -> d_out[0:RN]
    float r = H_STEP * (float)(j + 1);
    float base = 2.0f + 2.0f * s;                 // 2*(1 + ptl)
    D[j] = base;                                  // l = 0
    D[RN + j] = base + 4.0f / (r * r);            // l = 1: + 2*l(l+1)/r^2
    float mn = s, mx = s;
    for (int off = 32; off; off >>= 1) {
        mn = fminf(mn, __shfl_down(mn, off));
        mx = fmaxf(mx, __shfl_down(mx, off));
    }
    int tid = threadIdx.x;
    if ((tid & 63) == 0) { smn[tid >> 6] = mn; smx[tid >> 6] = mx; }
    __syncthreads();
    if (tid == 0) {
        for (int w = 1; w < 4; ++w) { mn = fminf(mn, smn[w]); mx = fmaxf(mx, smx[w]); }
        atomicMin(&bu[0], fmap(mn));
        atomicMax(&bu[1], fmap(mx));
    }
}

// -------- Sturm count via sign-alternating transform (NO negation in fma) ----
// p_i = (d_i - X) p_{i-1} - p_{i-2}. With u_i = sigma_i p_i, sigma = ++--
// (period 4): u_i = t'_i u_{i-1} + u_{i-2}, where t'_i = (d-X) for odd i and
// (X-d) for even i. Core step = v_sub + v_fma + v_alignbit, all plain encodings.
// Sign changes of p recovered from u's sign bits via constant mask 0x5555.
#define STEP_B(dv)                                                         \
    {                                                                      \
        float t = (dv) - X;                                                \
        float p = fmaf(t, pm1, pm2);                                       \
        r = __builtin_amdgcn_alignbit(r, __float_as_uint(p), 31);          \
        pm2 = pm1; pm1 = p;                                                \
    }
#define STEP_A(dv)                                                         \
    {                                                                      \
        float t = X - (dv);                                                \
        float p = fmaf(t, pm1, pm2);                                       \
        r = __builtin_amdgcn_alignbit(r, __float_as_uint(p), 31);          \
        pm2 = pm1; pm1 = p;                                                \
    }

// r bits 0..15: signs of u for this group's 16 steps (bit0 newest); bit16
// carries the previous group's newest sign. sigma-pattern correction = 0x5555.
#define CNT16                                                              \
    {                                                                      \
        unsigned xx = ((r ^ (r >> 1)) ^ 0x5555u) & 0xFFFFu;                \
        cnt += (unsigned)__builtin_popcount(xx);                           \
    }

#define RENORM                                                             \
    {                                                                      \
        unsigned a1 = __float_as_uint(pm1) & 0x7fffffffu;                  \
        unsigned a2 = __float_as_uint(pm2) & 0x7fffffffu;                  \
        unsigned hm = a1 > a2 ? a1 : a2;                                   \
        int es = 254 - (int)(hm >> 23);                                    \
        es = es < 1 ? 1 : es;                                              \
        float sc = __uint_as_float((unsigned)es << 23);                    \
        pm1 *= sc; pm2 *= sc;                                              \
    }

__global__ __launch_bounds__(256) void stage1(const float* __restrict__ Dall,
                                              const unsigned* __restrict__ bu,
                                              int* __restrict__ counts) {
    __shared__ alignas(16) float ds[RN];
    const float* Dsrc = Dall + (blockIdx.y << 12);   // D0 | D1
    for (int i = threadIdx.x; i < RN / 4; i += 256)
        reinterpret_cast<float4*>(ds)[i] = reinterpret_cast<const float4*>(Dsrc)[i];
    __syncthreads();

    float lo, cell;
    spect_bounds(bu, lo, cell);
    int j = blockIdx.x * 256 + threadIdx.x;          // 256 x-blocks -> j < 65536
    float X = 2.0f * (lo + cell * (float)j);

    float pm1 = 1.0f, pm2 = 0.0f;                    // u_0 = 1, u_{-1} = 0
    unsigned cnt = 0, r = 0;
    const float4* d4 = reinterpret_cast<const float4*>(ds);

    // 32 outer iters x 128 steps; 8 groups of 16 steps per iter.
    for (int w = 0; w < 32; ++w) {
        const float4* g = d4 + w * 32;
#pragma unroll
        for (int q = 0; q < 8; ++q) {
            float4 a = g[q * 4 + 0];
            float4 b2 = g[q * 4 + 1];
            float4 c2 = g[q * 4 + 2];
            float4 e2 = g[q * 4 + 3];
            STEP_B(a.x)  STEP_A(a.y)  STEP_B(a.z)  STEP_A(a.w)
            STEP_B(b2.x) STEP_A(b2.y) STEP_B(b2.z) STEP_A(b2.w)
            STEP_B(c2.x) STEP_A(c2.y) STEP_B(c2.z) STEP_A(c2.w)
            STEP_B(e2.x) STEP_A(e2.y) STEP_B(e2.z) STEP_A(e2.w)
            CNT16
            RENORM       // growth <= ~2^75 per 16 steps: safe in f32
        }
    }
    counts[(blockIdx.y << 16) + j] = (int)cnt;
}

// ------------- final: bracket search (noise-tolerant) + midpoint -------------
__global__ __launch_bounds__(256) void final_eig(const int* __restrict__ counts,
                                                 const unsigned* __restrict__ bu,
                                                 float* __restrict__ out) {
    int e = blockIdx.x * 256 + threadIdx.x;       // 8192 eigenvalues (l,k)
    int l = e >> 12, k = e & (RN - 1);
    const int* c = counts + (l << 16);
    int lo_i = 0, hi_i = G1 - 1;                  // last j with c[j] <= k
    while (lo_i < hi_i) {
        int mid = (lo_i + hi_i + 1) >> 1;
        if (c[mid] <= k) lo_i = mid; else hi_i = mid - 1;
    }
    while (lo_i > 0 && c[lo_i] > k) --lo_i;       // +-1 noise fixups
    while (lo_i < G1 - 1 && c[lo_i + 1] <= k) ++lo_i;
    float lo, cell;
    spect_bounds(bu, lo, cell);
    out[e] = lo + cell * ((float)lo_i + 0.5f);
}

extern "C" void kernel_launch(void* const* d_in, const int* in_sizes, int n_in,
                              void* d_out, int out_size, void* d_ws, size_t ws_size,
                              hipStream_t stream) {
    const float* energy = (const float*)d_in[0];
    const float* W1 = (const float*)d_in[1];
    const float* b1 = (const float*)d_in[2];
    const float* W2 = (const float*)d_in[3];
    const float* b2 = (const float*)d_in[4];
    const float* W3 = (const float*)d_in[5];
    const float* b3 = (const float*)d_in[6];
    float* out = (float*)d_out;                   // [RN] ptl, then [2*RN] eigenvalues

    float* ws = (float*)d_ws;
    float*    partA  = ws;                        // 131072 f32 (layers 1,3)
    float*    partB  = partA + 131072;            // 131072 f32 (layer 2)
    float*    D      = partB + 131072;            // 2*RN f32 (D0 | D1)
    unsigned* bu     = (unsigned*)(D + 2 * RN);   // 2 u32
    int*      counts = (int*)(bu + 4);            // 2*G1 i32 (512 KB)

    // ---- MLP: 3 GEMVs, fins fused into next layer's prologue ----
    part1 <<<dim3(8, 64),  256, 0, stream>>>(W1, energy, partA, bu);
    part2f<<<dim3(4, 128), 256, 0, stream>>>(W2, partA, b1, partB);
    part3f<<<dim3(16, 32), 256, 0, stream>>>(W3, partB, b2, partA);
    fin3  <<<RN / 256,     256, 0, stream>>>(partA, b3, out, D, bu);

    // ---- Eigenvalues: single-stage f32 Sturm multisection, 2 waves/SIMD ----
    stage1<<<dim3(G1 / 256, 2), 256, 0, stream>>>(D, bu, counts);
    final_eig<<<2 * RN / 256, 256, 0, stream>>>(counts, bu, out + RN);
}